// Round 17
// baseline (36.834 us; speedup 1.0000x reference)
//
#include <hip/hip_runtime.h>

#define BATCH 4
#define NS    512
#define XS    1024

#define NT    2048
#define RMAX  96.0f
#define HSTEP (RMAX / (float)NT)
#define INVH  ((float)NT / RMAX)

#define C2   2.8853900817779268f   // 2*log2(e)
#define NBLK 512

typedef float f32x4 __attribute__((ext_vector_type(4)));

__device__ __forceinline__ float bcast(float v, int lane) {   // compile-time lane
    return __builtin_bit_cast(float, __builtin_amdgcn_readlane(__builtin_bit_cast(int, v), lane));
}

// Single dispatch: 512 blocks x 512 threads (8 waves), >=2 blocks/CU resident.
//  Phase A: waves 0..3 build K[bid*4+wv] (lane=feature), store coherent (agent sc-bits).
//  Barrier: __syncthreads (drains vmcnt -> store acked at coherent point),
//           thread0 relaxed-agent fetch_add on counter; thread0 spins relaxed.
//           NO fences -> no L1/L2 invalidate storms (R14 lesson).
//  Phase B: copy K -> LDS (coherent loads), wave wv integrates xp=bid*8+wv.
extern "C" __global__ __launch_bounds__(512, 4)
void neurop_one(const float* __restrict__ yu, const float* __restrict__ x,
                const float* __restrict__ W_in, const float* __restrict__ b_in,
                const float* __restrict__ W_h, const float* __restrict__ b_h,
                const float* __restrict__ W_out, const float* __restrict__ b_out,
                float* __restrict__ K, unsigned int* __restrict__ counter,
                float* __restrict__ out)
{
    __shared__ float kl[NT];
    const int t   = threadIdx.x;
    const int l   = t & 63;
    const int wv  = t >> 6;
    const int bid = blockIdx.x;

    // ---------------- Phase A: waves 0..3 build K[bid*4+wv] ----------------
    if (wv < 4) {
        const int e  = bid * 4 + wv;
        const float r = (float)e * HSTEP;
        float h = fmaf(r, W_in[l], b_in[l]);

        #pragma unroll 1
        for (int d = 0; d < 6; ++d) {
            const float* __restrict__ W = W_h + (d << 12);   // W[i][j] row-major
            float hn = b_h[(d << 6) + l];
            #pragma unroll
            for (int i = 0; i < 64; ++i)
                hn = fmaf(bcast(h, i), W[(i << 6) + l], hn); // coalesced across lanes
            float ex = __builtin_amdgcn_exp2f(C2 * hn);      // tanh(z)=1-2/(exp2(C2 z)+1)
            float rc = __builtin_amdgcn_rcpf(ex + 1.0f);
            h = fmaf(-2.0f, rc, h + 1.0f);
        }

        float p = h * W_out[l];
        #pragma unroll
        for (int off = 1; off < 64; off <<= 1)
            p += __shfl_xor(p, off);
        if (l == 0)
            __hip_atomic_store(&K[e], p + b_out[0],
                               __ATOMIC_RELAXED, __HIP_MEMORY_SCOPE_AGENT);
    }
    __syncthreads();   // emits s_waitcnt vmcnt(0) before s_barrier: K store acked

    // ---------------- arrival + single-spinner barrier ----------------
    if (t == 0) {
        __hip_atomic_fetch_add(counter, 1u, __ATOMIC_RELAXED, __HIP_MEMORY_SCOPE_AGENT);
        while (__hip_atomic_load(counter, __ATOMIC_RELAXED, __HIP_MEMORY_SCOPE_AGENT) < NBLK)
            __builtin_amdgcn_s_sleep(2);
    }
    __syncthreads();

    // ---------------- copy K to LDS (coherent, coalesced) ----------------
    #pragma unroll
    for (int q = 0; q < NT / 512; ++q) {
        const int idx = q * 512 + t;
        kl[idx] = __hip_atomic_load(&K[idx], __ATOMIC_RELAXED, __HIP_MEMORY_SCOPE_AGENT);
    }
    __syncthreads();

    // ---------------- Phase B: integrate xp = bid*8+wv ----------------
    {
        const int xp = bid * 8 + wv;       // b*XS + xi
        const int b  = xp >> 10;
        const float x0 = x[xp * 2 + 0];
        const float x1 = x[xp * 2 + 1];

        float a0 = 0.0f, a1 = 0.0f, a2 = 0.0f;
        #pragma unroll
        for (int c = 0; c < 8; ++c) {
            const int s = c * 64 + l;
            const float* ur = yu + (b * NS + s) * 5;
            f32x4 uy;                      // u0,u1,u2,y0 (4B-aligned 16B load)
            __builtin_memcpy(&uy, ur, 16);
            const float y1v = ur[4];
            const float d0 = x0 - uy.w, d1 = x1 - y1v;
            const float r  = d0 * d0 + d1 * d1;

            float tt = fminf(r * INVH, (float)NT - 1.5f);   // i <= NT-2
            int   i  = (int)tt;
            float f  = tt - (float)i;
            float k0 = kl[i], k1 = kl[i + 1];
            float k  = fmaf(f, k1 - k0, k0);

            a0 = fmaf(k, uy.x, a0);
            a1 = fmaf(k, uy.y, a1);
            a2 = fmaf(k, uy.z, a2);
        }
        #pragma unroll
        for (int off = 1; off < 64; off <<= 1) {
            a0 += __shfl_xor(a0, off);
            a1 += __shfl_xor(a1, off);
            a2 += __shfl_xor(a2, off);
        }
        if (l == 0) {
            out[xp * 3 + 0] = a0 * (1.0f / (float)NS);
            out[xp * 3 + 1] = a1 * (1.0f / (float)NS);
            out[xp * 3 + 2] = a2 * (1.0f / (float)NS);
        }
    }
}

extern "C" void kernel_launch(void* const* d_in, const int* in_sizes, int n_in,
                              void* d_out, int out_size, void* d_ws, size_t ws_size,
                              hipStream_t stream) {
    const float* yu    = (const float*)d_in[0];
    const float* x     = (const float*)d_in[1];
    const float* W_in  = (const float*)d_in[2];
    const float* b_in  = (const float*)d_in[3];
    const float* W_h   = (const float*)d_in[4];
    const float* b_h   = (const float*)d_in[5];
    const float* W_out = (const float*)d_in[6];
    const float* b_out = (const float*)d_in[7];
    float* out = (float*)d_out;
    float*        K       = (float*)d_ws;                         // 2048*4 = 8 KB
    unsigned int* counter = (unsigned int*)((char*)d_ws + 8192);  // 4 B

    (void)hipMemsetAsync(counter, 0, 4, stream);   // graph-legal; resets barrier
    hipLaunchKernelGGL(neurop_one, dim3(NBLK), dim3(512), 0, stream,
                       yu, x, W_in, b_in, W_h, b_h, W_out, b_out, K, counter, out);
}